// Round 13
// baseline (231.869 us; speedup 1.0000x reference)
//
#include <hip/hip_runtime.h>
#include <hip/hip_bf16.h>
#include <cstdint>
#include <cmath>

#define AS1 __attribute__((address_space(1)))
#define AS3 __attribute__((address_space(3)))

typedef unsigned short u16;
typedef uint32_t u32;
typedef __attribute__((ext_vector_type(8))) __bf16 bf16x8;
typedef __attribute__((ext_vector_type(8))) unsigned short u16x8;
typedef __attribute__((ext_vector_type(4))) float f32x4;

// fp32 -> bf16 round-to-nearest-even
__device__ __forceinline__ u16 f2bf(float f) {
    uint32_t u = __builtin_bit_cast(uint32_t, f);
    return (u16)((u + 0x7fffu + ((u >> 16) & 1u)) >> 16);
}

// order-preserving float -> u32 map (for integer atomicMax); 0 is below all reals
__device__ __forceinline__ u32 f2ord(float f) {
    u32 u = __builtin_bit_cast(u32, f);
    return u ^ (u32)(((int32_t)u >> 31) | 0x80000000);
}
__device__ __forceinline__ float ord2f(u32 v) {
    u32 u = (v & 0x80000000u) ? (v ^ 0x80000000u) : ~v;
    return __builtin_bit_cast(float, u);
}

// ---------------- fused setup ----------------
// ALGEBRA: relu(h)=(h+|h|)/2, relu(-h)=(|h|-h)/2  =>
//   leaf = |h| @ Ws^T + x @ Wc^T + cl
// R13: wsb/dlb/cl fused into ONE pass over Wl (reads each Wl row once).
// blocks [0,2048):    x [32768,128] fp32 -> bf16 xb
// blocks [2048,2112): w1b [1024,128] + bias bb[1024] + w1t = W1^T [128,1024]
// blocks [2112,2624): per 2 leaf rows: wsb=(a+b)/2, dlb=a-b (bf16), cl=0.5*dl@b1
__global__ void setup_all(const float* __restrict__ x,
                          const float* __restrict__ Wd, const float* __restrict__ bd,
                          const float* __restrict__ Wa, const float* __restrict__ ba,
                          const float* __restrict__ Wl,
                          u16* __restrict__ xb, u16* __restrict__ w1b,
                          float* __restrict__ bb, u16* __restrict__ w1t,
                          u16* __restrict__ wsb, u16* __restrict__ dlb,
                          float* __restrict__ cl) {
    __shared__ float cred[256];
    const int b = blockIdx.x;
    const int tid = threadIdx.x;
    if (b < 2048) {
        long idx = (long)(b * 256 + tid) * 8;
        float4 a = *(const float4*)(x + idx);
        float4 c = *(const float4*)(x + idx + 4);
        u16x8 o;
        o[0]=f2bf(a.x); o[1]=f2bf(a.y); o[2]=f2bf(a.z); o[3]=f2bf(a.w);
        o[4]=f2bf(c.x); o[5]=f2bf(c.y); o[6]=f2bf(c.z); o[7]=f2bf(c.w);
        *(u16x8*)(xb + idx) = o;
    } else if (b < 2112) {
        int t = (b - 2048) * 256 + tid;   // 16384 threads
        int row = t >> 4, g = (t & 15) * 8;
        const float* src = nullptr;
        if (row < 511)       src = Wd + row * 128 + g;
        else if (row < 1023) src = Wa + (row - 511) * 128 + g;
        u16x8 o = 0;
        if (src) {
            #pragma unroll
            for (int j = 0; j < 8; ++j) o[j] = f2bf(src[j]);
        }
        *(u16x8*)(w1b + row * 128 + g) = o;
        #pragma unroll
        for (int j = 0; j < 8; ++j) w1t[(g + j) * 1024 + row] = o[j];
        if ((t & 15) == 0)
            bb[row] = row < 511 ? bd[row] : (row < 1023 ? ba[row - 511] : 0.f);
    } else {
        const int l0 = (b - 2112) * 2;
        const int lo = tid >> 7, g = (tid & 127) * 8;
        const float* src = Wl + (long)(l0 + lo) * 2046;
        u16x8 os, od;
        float part = 0.f;
        #pragma unroll
        for (int j = 0; j < 8; ++j) {
            int c = g + j;
            float pa = 0.f, pb = 0.f;
            if (c < 1023) { pa = src[c]; pb = src[1023 + c]; }
            os[j] = f2bf(0.5f * (pa + pb));
            float v = pa - pb;
            od[j] = f2bf(v);
            float b1 = c < 511 ? bd[c] : (c < 1023 ? ba[c - 511] : 0.f);
            part += v * b1;
        }
        *(u16x8*)(wsb + (long)(l0 + lo) * 1024 + g) = os;
        *(u16x8*)(dlb + (long)(l0 + lo) * 1024 + g) = od;
        cred[tid] = part;
        __syncthreads();
        if (tid < 2) {
            float s = 0.f;
            #pragma unroll
            for (int k = 0; k < 128; ++k) s += cred[tid * 128 + k];
            cl[l0 + tid] = 0.5f * s;
        }
    }
}

// ---------------- gemm_hwc: fused habs-GEMM + Wc-GEMM ----------------
// y < 256: habs = |xb @ w1b^T + bb| [32768,1024]. R13: BK=64 (2 drains instead of 4,
//   the r12-validated drain-amortization lever). LDS union {2x(A,B) 32KB | obuf 33.8KB}
//   -> 4 blocks/CU. Epilogue: stage to obuf, 8x coalesced 16B stores/thread.
// y == 256: Wc = 0.5 * dlb @ w1t^T [1024,128], 8 blocks, K=1024 looped (panel 0).
__global__ __launch_bounds__(256) void gemm_hwc(
        const u16* __restrict__ xb, const u16* __restrict__ w1b,
        const float* __restrict__ bb,
        const u16* __restrict__ dlb, const u16* __restrict__ w1t,
        u16* __restrict__ habs, u16* __restrict__ wcb) {
    __shared__ union SharedU {
        struct { u16 As[2][4096]; u16 Bs[2][4096]; } s;  // 32 KB, 2 K-panels of 32
        u16 obuf[128 * 132];                             // 33.8 KB epilogue overlay
    } sh;
    const int tid  = threadIdx.x;
    const int lane = tid & 63, wave = tid >> 6;
    const int wy = wave >> 1, wx = wave & 1;
    const int i16 = lane & 15, q = lane >> 4;
    const int cA = wave * 2, srow = lane >> 2, scol = (lane & 3) * 8;

    f32x4 acc[4][4];
    #pragma unroll
    for (int m = 0; m < 4; ++m)
        #pragma unroll
        for (int n = 0; n < 4; ++n) acc[m][n] = f32x4{0.f,0.f,0.f,0.f};

    if (blockIdx.y == 256) {
        // ---- wc role: Wc = 0.5*dlb@w1t^T, K=1024, BK=32 in panel 0 ----
        const long blockM = (long)blockIdx.x * 128;
        const int koff = (blockIdx.x * 4) & 31;
        const u16* a0 = dlb + (blockM + cA * 16 + srow) * 1024 + scol;
        const u16* a1 = dlb + (blockM + (cA + 1) * 16 + srow) * 1024 + scol;
        const u16* b0 = w1t + (long)(cA * 16 + srow) * 1024 + scol;
        const u16* b1 = w1t + (long)((cA + 1) * 16 + srow) * 1024 + scol;
        for (int it = 0; it < 32; ++it) {
            const int k0 = ((it + koff) & 31) << 5;
            __builtin_amdgcn_global_load_lds((const AS1 void*)(a0 + k0), (AS3 void*)&sh.s.As[0][cA * 512],       16, 0, 0);
            __builtin_amdgcn_global_load_lds((const AS1 void*)(a1 + k0), (AS3 void*)&sh.s.As[0][(cA + 1) * 512], 16, 0, 0);
            __builtin_amdgcn_global_load_lds((const AS1 void*)(b0 + k0), (AS3 void*)&sh.s.Bs[0][cA * 512],       16, 0, 0);
            __builtin_amdgcn_global_load_lds((const AS1 void*)(b1 + k0), (AS3 void*)&sh.s.Bs[0][(cA + 1) * 512], 16, 0, 0);
            __syncthreads();
            bf16x8 af[4], bfv[4];
            #pragma unroll
            for (int s = 0; s < 4; ++s) {
                af[s]  = *(const bf16x8*)&sh.s.As[0][(wy * 64 + s * 16 + i16) * 32 + q * 8];
                bfv[s] = *(const bf16x8*)&sh.s.Bs[0][(wx * 64 + s * 16 + i16) * 32 + q * 8];
            }
            #pragma unroll
            for (int sm = 0; sm < 4; ++sm)
                #pragma unroll
                for (int sn = 0; sn < 4; ++sn)
                    acc[sm][sn] = __builtin_amdgcn_mfma_f32_16x16x32_bf16(af[sm], bfv[sn], acc[sm][sn], 0, 0, 0);
            __syncthreads();
        }
        #pragma unroll
        for (int sm = 0; sm < 4; ++sm)
            #pragma unroll
            for (int sn = 0; sn < 4; ++sn) {
                const int col = wx * 64 + sn * 16 + i16;     // 0..127
                #pragma unroll
                for (int r = 0; r < 4; ++r) {
                    const long row = blockM + wy * 64 + sm * 16 + 4 * q + r;
                    wcb[row * 128 + col] = f2bf(0.5f * acc[sm][sn][r]);
                }
            }
        return;
    }

    // ---- h role: habs = |xb @ w1b^T + bb|, BK=64 x 2 iters ----
    const int xcd = blockIdx.x, y = blockIdx.y;
    const long blockM = (long)(xcd * 32 + (y >> 3)) * 128;
    const int  blockN = (y & 7) * 128;
    const int  koff = (y >> 3) & 1;

    const u16* a0 = xb + (blockM + cA * 16 + srow) * 128 + scol;
    const u16* a1 = xb + (blockM + (cA + 1) * 16 + srow) * 128 + scol;
    const u16* b0 = w1b + ((long)blockN + cA * 16 + srow) * 128 + scol;
    const u16* b1 = w1b + ((long)blockN + (cA + 1) * 16 + srow) * 128 + scol;
    for (int it = 0; it < 2; ++it) {
        const int k0 = ((it + koff) & 1) << 6;
        #pragma unroll
        for (int p = 0; p < 2; ++p) {
            const int kp = k0 + p * 32;
            __builtin_amdgcn_global_load_lds((const AS1 void*)(a0 + kp), (AS3 void*)&sh.s.As[p][cA * 512],       16, 0, 0);
            __builtin_amdgcn_global_load_lds((const AS1 void*)(a1 + kp), (AS3 void*)&sh.s.As[p][(cA + 1) * 512], 16, 0, 0);
            __builtin_amdgcn_global_load_lds((const AS1 void*)(b0 + kp), (AS3 void*)&sh.s.Bs[p][cA * 512],       16, 0, 0);
            __builtin_amdgcn_global_load_lds((const AS1 void*)(b1 + kp), (AS3 void*)&sh.s.Bs[p][(cA + 1) * 512], 16, 0, 0);
        }
        __syncthreads();
        #pragma unroll
        for (int p = 0; p < 2; ++p) {
            bf16x8 af[4], bfv[4];
            #pragma unroll
            for (int s = 0; s < 4; ++s) {
                af[s]  = *(const bf16x8*)&sh.s.As[p][(wy * 64 + s * 16 + i16) * 32 + q * 8];
                bfv[s] = *(const bf16x8*)&sh.s.Bs[p][(wx * 64 + s * 16 + i16) * 32 + q * 8];
            }
            #pragma unroll
            for (int sm = 0; sm < 4; ++sm)
                #pragma unroll
                for (int sn = 0; sn < 4; ++sn)
                    acc[sm][sn] = __builtin_amdgcn_mfma_f32_16x16x32_bf16(af[sm], bfv[sn], acc[sm][sn], 0, 0, 0);
        }
        __syncthreads();   // also guards obuf overlay of As/Bs
    }

    float bv[4];
    #pragma unroll
    for (int sn = 0; sn < 4; ++sn) bv[sn] = bb[blockN + wx * 64 + sn * 16 + i16];
    #pragma unroll
    for (int sm = 0; sm < 4; ++sm)
        #pragma unroll
        for (int sn = 0; sn < 4; ++sn)
            #pragma unroll
            for (int r = 0; r < 4; ++r)
                sh.obuf[(wy * 64 + sm * 16 + 4 * q + r) * 132 + wx * 64 + sn * 16 + i16] =
                    f2bf(fabsf(acc[sm][sn][r] + bv[sn]));
    __syncthreads();
    const int cg = (tid & 15) * 8;
    #pragma unroll
    for (int it = 0; it < 8; ++it) {
        const int row = it * 16 + (tid >> 4);
        *(u16x8*)&habs[(blockM + row) * 1024 + blockN + cg] =
            *(const u16x8*)&sh.obuf[row * 132 + cg];
    }
}

// ---------------- GEMM2': leaf = habs@Ws^T + xb@Wc^T + cl, fused ragged-max ----------
// R12 BK=64 structure; R13: phase-1 loop split into two LINEAR segments (same k0 set,
// rotation preserved) so the compiler strength-reduces the load addresses.
__global__ __launch_bounds__(256) void gemm_leaf(const u16* __restrict__ habs,
        const u16* __restrict__ xb, const u16* __restrict__ wsb,
        const u16* __restrict__ wcb, const float* __restrict__ cl,
        const int* __restrict__ seg, u32* __restrict__ pp) {
    __shared__ u16 As[2][128 * 32];
    __shared__ u16 Bs[2][128 * 32];
    __shared__ u32 pmax[128 * 16];
    const int tid  = threadIdx.x;
    const int lane = tid & 63, wave = tid >> 6;
    const int wy = wave >> 1, wx = wave & 1;
    const int i16 = lane & 15, q = lane >> 4;
    const int xcd = blockIdx.x, y = blockIdx.y;
    const int nTile = y & 7;
    const long blockM = (long)(xcd * 32 + (y >> 3)) * 128;
    const int  blockN = nTile * 128;
    const int  koff = ((y >> 3) * 2) & 15;        // rotation over 16 chunks of K=64

    #pragma unroll
    for (int j = 0; j < 8; ++j) pmax[tid + j * 256] = 0u;   // below all reals

    f32x4 acc[4][4];
    #pragma unroll
    for (int m = 0; m < 4; ++m)
        #pragma unroll
        for (int n = 0; n < 4; ++n) acc[m][n] = f32x4{0.f,0.f,0.f,0.f};

    const int cA = wave * 2, srow = lane >> 2, scol = (lane & 3) * 8;
    // phase 1: habs (stride 1024) x wsb (stride 1024), 16 iters of K=64 (two linear runs)
    {
        const u16* a0 = habs + (blockM + cA * 16 + srow) * 1024 + scol;
        const u16* a1 = habs + (blockM + (cA + 1) * 16 + srow) * 1024 + scol;
        const u16* b0 = wsb + ((long)blockN + cA * 16 + srow) * 1024 + scol;
        const u16* b1 = wsb + ((long)blockN + (cA + 1) * 16 + srow) * 1024 + scol;
        auto kstep = [&](int k0) {
            #pragma unroll
            for (int p = 0; p < 2; ++p) {
                const int kp = k0 + p * 32;
                __builtin_amdgcn_global_load_lds((const AS1 void*)(a0 + kp), (AS3 void*)&As[p][cA * 512],       16, 0, 0);
                __builtin_amdgcn_global_load_lds((const AS1 void*)(a1 + kp), (AS3 void*)&As[p][(cA + 1) * 512], 16, 0, 0);
                __builtin_amdgcn_global_load_lds((const AS1 void*)(b0 + kp), (AS3 void*)&Bs[p][cA * 512],       16, 0, 0);
                __builtin_amdgcn_global_load_lds((const AS1 void*)(b1 + kp), (AS3 void*)&Bs[p][(cA + 1) * 512], 16, 0, 0);
            }
            __syncthreads();
            #pragma unroll
            for (int p = 0; p < 2; ++p) {
                bf16x8 af[4], bfv[4];
                #pragma unroll
                for (int s = 0; s < 4; ++s) {
                    af[s]  = *(const bf16x8*)&As[p][(wy * 64 + s * 16 + i16) * 32 + q * 8];
                    bfv[s] = *(const bf16x8*)&Bs[p][(wx * 64 + s * 16 + i16) * 32 + q * 8];
                }
                #pragma unroll
                for (int sm = 0; sm < 4; ++sm)
                    #pragma unroll
                    for (int sn = 0; sn < 4; ++sn)
                        acc[sm][sn] = __builtin_amdgcn_mfma_f32_16x16x32_bf16(af[sm], bfv[sn], acc[sm][sn], 0, 0, 0);
            }
            __syncthreads();
        };
        for (int it = koff; it < 16; ++it) kstep(it << 6);
        for (int it = 0; it < koff; ++it)  kstep(it << 6);
    }
    // phase 2: xb (stride 128) x wcb (stride 128), 2 iters of K=64
    {
        const u16* a0 = xb + (blockM + cA * 16 + srow) * 128 + scol;
        const u16* a1 = xb + (blockM + (cA + 1) * 16 + srow) * 128 + scol;
        const u16* b0 = wcb + ((long)blockN + cA * 16 + srow) * 128 + scol;
        const u16* b1 = wcb + ((long)blockN + (cA + 1) * 16 + srow) * 128 + scol;
        #pragma unroll
        for (int half = 0; half < 2; ++half) {
            const int k0 = half * 64;
            #pragma unroll
            for (int p = 0; p < 2; ++p) {
                const int kp = k0 + p * 32;
                __builtin_amdgcn_global_load_lds((const AS1 void*)(a0 + kp), (AS3 void*)&As[p][cA * 512],       16, 0, 0);
                __builtin_amdgcn_global_load_lds((const AS1 void*)(a1 + kp), (AS3 void*)&As[p][(cA + 1) * 512], 16, 0, 0);
                __builtin_amdgcn_global_load_lds((const AS1 void*)(b0 + kp), (AS3 void*)&Bs[p][cA * 512],       16, 0, 0);
                __builtin_amdgcn_global_load_lds((const AS1 void*)(b1 + kp), (AS3 void*)&Bs[p][(cA + 1) * 512], 16, 0, 0);
            }
            __syncthreads();
            #pragma unroll
            for (int p = 0; p < 2; ++p) {
                bf16x8 af[4], bfv[4];
                #pragma unroll
                for (int s = 0; s < 4; ++s) {
                    af[s]  = *(const bf16x8*)&As[p][(wy * 64 + s * 16 + i16) * 32 + q * 8];
                    bfv[s] = *(const bf16x8*)&Bs[p][(wx * 64 + s * 16 + i16) * 32 + q * 8];
                }
                #pragma unroll
                for (int sm = 0; sm < 4; ++sm)
                    #pragma unroll
                    for (int sn = 0; sn < 4; ++sn)
                        acc[sm][sn] = __builtin_amdgcn_mfma_f32_16x16x32_bf16(af[sm], bfv[sn], acc[sm][sn], 0, 0, 0);
            }
            __syncthreads();
        }
    }

    // epilogue: D[row = 4q + r][col = i16]; leaf = acc + cl[col]
    int segc[4]; float clv[4];
    #pragma unroll
    for (int sn = 0; sn < 4; ++sn) {
        const int col = blockN + wx * 64 + sn * 16 + i16;
        segc[sn] = seg[col];
        clv[sn]  = cl[col];
    }
    #pragma unroll
    for (int sm = 0; sm < 4; ++sm)
        #pragma unroll
        for (int sn = 0; sn < 4; ++sn)
            #pragma unroll
            for (int r = 0; r < 4; ++r) {
                const int rl = wy * 64 + sm * 16 + 4 * q + r;
                atomicMax(&pmax[rl * 16 + segc[sn]], f2ord(acc[sm][sn][r] + clv[sn]));
            }
    __syncthreads();
    #pragma unroll
    for (int j = 0; j < 8; ++j) {
        int idx = tid + j * 256;                       // 0..2047
        pp[((long)nTile << 19) + ((blockM + (idx >> 4)) << 4) + (idx & 15)] = pmax[idx];
    }
}

// ---------------- finalize: max over 8 partials + softmax ----------------
__global__ __launch_bounds__(256) void finalize(const u32* __restrict__ pp,
                                                float* __restrict__ out) {
    const int tid = threadIdx.x;
    const long row = (long)blockIdx.x * 16 + (tid >> 4);
    const int t = tid & 15;
    u32 m = 0;
    #pragma unroll
    for (int p = 0; p < 8; ++p)
        m = max(m, pp[((long)p << 19) + (row << 4) + t]);
    float logit = ord2f(m);
    float rm = logit;
    #pragma unroll
    for (int d = 8; d >= 1; d >>= 1) rm = fmaxf(rm, __shfl_xor(rm, d, 16));
    float e = __expf(logit - rm);
    float s = e;
    #pragma unroll
    for (int d = 8; d >= 1; d >>= 1) s += __shfl_xor(s, d, 16);
    out[(row << 4) + t] = e / s;
}

// ---------------- launch ----------------
extern "C" void kernel_launch(void* const* d_in, const int* in_sizes, int n_in,
                              void* d_out, int out_size, void* d_ws, size_t ws_size,
                              hipStream_t stream) {
    const float* x  = (const float*)d_in[0];
    const float* Wd = (const float*)d_in[1];
    const float* bd = (const float*)d_in[2];
    const float* Wa = (const float*)d_in[3];
    const float* ba = (const float*)d_in[4];
    const float* Wl = (const float*)d_in[5];
    const int*  seg = (const int*)d_in[6];
    float* out = (float*)d_out;

    char* ws = (char*)d_ws;
    u16*   xb   = (u16*)(ws);                      //   8,388,608 B  x bf16 [32768,128]
    u16*   w1b  = (u16*)(ws + 8388608);            //     262,144 B  W1 bf16 [1024,128]
    float* bb   = (float*)(ws + 8650752);          //       4,096 B  bias [1024]
    u16*   w1t  = (u16*)(ws + 8654848);            //     262,144 B  W1^T bf16 [128,1024]
    u16*   wsb  = (u16*)(ws + 8916992);            //   2,097,152 B  Ws bf16 [1024,1024]
    u16*   dlb  = (u16*)(ws + 11014144);           //   2,097,152 B  Dl bf16 [1024,1024]
    u16*   wcb  = (u16*)(ws + 13111296);           //     262,144 B  Wc bf16 [1024,128]
    float* clp  = (float*)(ws + 13373440);         //       4,096 B  cl fp32 [1024]
    u16*   habs = (u16*)(ws + 13377536);           //  67,108,864 B  |h| bf16 [32768,1024]
    u32*   pp   = (u32*)(ws + 80486400);           //  16,777,216 B  pooledPart u32 [8][32768][16]
    // total ws use: 97,263,616 B (~93 MiB)

    setup_all<<<2624, 256, 0, stream>>>(x, Wd, bd, Wa, ba, Wl,
                                        xb, w1b, bb, w1t, wsb, dlb, clp);
    gemm_hwc <<<dim3(8, 257), 256, 0, stream>>>(xb, w1b, bb, dlb, w1t, habs, wcb);
    gemm_leaf<<<dim3(8, 256), 256, 0, stream>>>(habs, xb, wsb, wcb, clp, seg, pp);
    finalize <<<2048, 256, 0, stream>>>(pp, out);
}

// Round 14
// 211.182 us; speedup vs baseline: 1.0980x; 1.0980x over previous
//
#include <hip/hip_runtime.h>
#include <hip/hip_bf16.h>
#include <cstdint>
#include <cmath>

#define AS1 __attribute__((address_space(1)))
#define AS3 __attribute__((address_space(3)))

typedef unsigned short u16;
typedef uint32_t u32;
typedef __attribute__((ext_vector_type(8))) __bf16 bf16x8;
typedef __attribute__((ext_vector_type(8))) unsigned short u16x8;
typedef __attribute__((ext_vector_type(4))) float f32x4;

// fp32 -> bf16 round-to-nearest-even
__device__ __forceinline__ u16 f2bf(float f) {
    uint32_t u = __builtin_bit_cast(uint32_t, f);
    return (u16)((u + 0x7fffu + ((u >> 16) & 1u)) >> 16);
}

// order-preserving float -> u32 map (for integer atomicMax); 0 is below all reals
__device__ __forceinline__ u32 f2ord(float f) {
    u32 u = __builtin_bit_cast(u32, f);
    return u ^ (u32)(((int32_t)u >> 31) | 0x80000000);
}
__device__ __forceinline__ float ord2f(u32 v) {
    u32 u = (v & 0x80000000u) ? (v ^ 0x80000000u) : ~v;
    return __builtin_bit_cast(float, u);
}

// ---------------- fused setup (control, = r13) ----------------
// ALGEBRA: relu(h)=(h+|h|)/2, relu(-h)=(|h|-h)/2  =>
//   leaf = |h| @ Ws^T + x @ Wc^T + cl
__global__ void setup_all(const float* __restrict__ x,
                          const float* __restrict__ Wd, const float* __restrict__ bd,
                          const float* __restrict__ Wa, const float* __restrict__ ba,
                          const float* __restrict__ Wl,
                          u16* __restrict__ xb, u16* __restrict__ w1b,
                          float* __restrict__ bb, u16* __restrict__ w1t,
                          u16* __restrict__ wsb, u16* __restrict__ dlb,
                          float* __restrict__ cl) {
    __shared__ float cred[256];
    const int b = blockIdx.x;
    const int tid = threadIdx.x;
    if (b < 2048) {
        long idx = (long)(b * 256 + tid) * 8;
        float4 a = *(const float4*)(x + idx);
        float4 c = *(const float4*)(x + idx + 4);
        u16x8 o;
        o[0]=f2bf(a.x); o[1]=f2bf(a.y); o[2]=f2bf(a.z); o[3]=f2bf(a.w);
        o[4]=f2bf(c.x); o[5]=f2bf(c.y); o[6]=f2bf(c.z); o[7]=f2bf(c.w);
        *(u16x8*)(xb + idx) = o;
    } else if (b < 2112) {
        int t = (b - 2048) * 256 + tid;   // 16384 threads
        int row = t >> 4, g = (t & 15) * 8;
        const float* src = nullptr;
        if (row < 511)       src = Wd + row * 128 + g;
        else if (row < 1023) src = Wa + (row - 511) * 128 + g;
        u16x8 o = 0;
        if (src) {
            #pragma unroll
            for (int j = 0; j < 8; ++j) o[j] = f2bf(src[j]);
        }
        *(u16x8*)(w1b + row * 128 + g) = o;
        #pragma unroll
        for (int j = 0; j < 8; ++j) w1t[(g + j) * 1024 + row] = o[j];
        if ((t & 15) == 0)
            bb[row] = row < 511 ? bd[row] : (row < 1023 ? ba[row - 511] : 0.f);
    } else {
        const int l0 = (b - 2112) * 2;
        const int lo = tid >> 7, g = (tid & 127) * 8;
        const float* src = Wl + (long)(l0 + lo) * 2046;
        u16x8 os, od;
        float part = 0.f;
        #pragma unroll
        for (int j = 0; j < 8; ++j) {
            int c = g + j;
            float pa = 0.f, pb = 0.f;
            if (c < 1023) { pa = src[c]; pb = src[1023 + c]; }
            os[j] = f2bf(0.5f * (pa + pb));
            float v = pa - pb;
            od[j] = f2bf(v);
            float b1 = c < 511 ? bd[c] : (c < 1023 ? ba[c - 511] : 0.f);
            part += v * b1;
        }
        *(u16x8*)(wsb + (long)(l0 + lo) * 1024 + g) = os;
        *(u16x8*)(dlb + (long)(l0 + lo) * 1024 + g) = od;
        cred[tid] = part;
        __syncthreads();
        if (tid < 2) {
            float s = 0.f;
            #pragma unroll
            for (int k = 0; k < 128; ++k) s += cred[tid * 128 + k];
            cl[l0 + tid] = 0.5f * s;
        }
    }
}

// ---------------- gemm_hwc: fused habs-GEMM + Wc-GEMM ----------------
// R14: wc role moved to blockIdx.y == 0 so its 8 long-running blocks (K=1024, 32 serial
// drains, 1 block/CU) are dispatched FIRST and overlap with the 2048 h-role blocks.
// (r13 had wc at y==256 -> dispatched last -> ~15 us serial tail after h drained.)
// y == 0 : Wc = 0.5 * dlb @ w1t^T [1024,128], 8 blocks, K=1024 looped (panel 0).
// y >= 1 : habs = |xb @ w1b^T + bb| [32768,1024], BK=64 x 2 iters, obuf union epilogue.
__global__ __launch_bounds__(256) void gemm_hwc(
        const u16* __restrict__ xb, const u16* __restrict__ w1b,
        const float* __restrict__ bb,
        const u16* __restrict__ dlb, const u16* __restrict__ w1t,
        u16* __restrict__ habs, u16* __restrict__ wcb) {
    __shared__ union SharedU {
        struct { u16 As[2][4096]; u16 Bs[2][4096]; } s;  // 32 KB, 2 K-panels of 32
        u16 obuf[128 * 132];                             // 33.8 KB epilogue overlay
    } sh;
    const int tid  = threadIdx.x;
    const int lane = tid & 63, wave = tid >> 6;
    const int wy = wave >> 1, wx = wave & 1;
    const int i16 = lane & 15, q = lane >> 4;
    const int cA = wave * 2, srow = lane >> 2, scol = (lane & 3) * 8;

    f32x4 acc[4][4];
    #pragma unroll
    for (int m = 0; m < 4; ++m)
        #pragma unroll
        for (int n = 0; n < 4; ++n) acc[m][n] = f32x4{0.f,0.f,0.f,0.f};

    if (blockIdx.y == 0) {
        // ---- wc role: Wc = 0.5*dlb@w1t^T, K=1024, BK=32 in panel 0 ----
        const long blockM = (long)blockIdx.x * 128;
        const int koff = (blockIdx.x * 4) & 31;
        const u16* a0 = dlb + (blockM + cA * 16 + srow) * 1024 + scol;
        const u16* a1 = dlb + (blockM + (cA + 1) * 16 + srow) * 1024 + scol;
        const u16* b0 = w1t + (long)(cA * 16 + srow) * 1024 + scol;
        const u16* b1 = w1t + (long)((cA + 1) * 16 + srow) * 1024 + scol;
        for (int it = 0; it < 32; ++it) {
            const int k0 = ((it + koff) & 31) << 5;
            __builtin_amdgcn_global_load_lds((const AS1 void*)(a0 + k0), (AS3 void*)&sh.s.As[0][cA * 512],       16, 0, 0);
            __builtin_amdgcn_global_load_lds((const AS1 void*)(a1 + k0), (AS3 void*)&sh.s.As[0][(cA + 1) * 512], 16, 0, 0);
            __builtin_amdgcn_global_load_lds((const AS1 void*)(b0 + k0), (AS3 void*)&sh.s.Bs[0][cA * 512],       16, 0, 0);
            __builtin_amdgcn_global_load_lds((const AS1 void*)(b1 + k0), (AS3 void*)&sh.s.Bs[0][(cA + 1) * 512], 16, 0, 0);
            __syncthreads();
            bf16x8 af[4], bfv[4];
            #pragma unroll
            for (int s = 0; s < 4; ++s) {
                af[s]  = *(const bf16x8*)&sh.s.As[0][(wy * 64 + s * 16 + i16) * 32 + q * 8];
                bfv[s] = *(const bf16x8*)&sh.s.Bs[0][(wx * 64 + s * 16 + i16) * 32 + q * 8];
            }
            #pragma unroll
            for (int sm = 0; sm < 4; ++sm)
                #pragma unroll
                for (int sn = 0; sn < 4; ++sn)
                    acc[sm][sn] = __builtin_amdgcn_mfma_f32_16x16x32_bf16(af[sm], bfv[sn], acc[sm][sn], 0, 0, 0);
            __syncthreads();
        }
        #pragma unroll
        for (int sm = 0; sm < 4; ++sm)
            #pragma unroll
            for (int sn = 0; sn < 4; ++sn) {
                const int col = wx * 64 + sn * 16 + i16;     // 0..127
                #pragma unroll
                for (int r = 0; r < 4; ++r) {
                    const long row = blockM + wy * 64 + sm * 16 + 4 * q + r;
                    wcb[row * 128 + col] = f2bf(0.5f * acc[sm][sn][r]);
                }
            }
        return;
    }

    // ---- h role: habs = |xb @ w1b^T + bb|, BK=64 x 2 iters ----
    const int xcd = blockIdx.x, yy = blockIdx.y - 1;   // yy in 0..255
    const long blockM = (long)(xcd * 32 + (yy >> 3)) * 128;
    const int  blockN = (yy & 7) * 128;
    const int  koff = (yy >> 3) & 1;

    const u16* a0 = xb + (blockM + cA * 16 + srow) * 128 + scol;
    const u16* a1 = xb + (blockM + (cA + 1) * 16 + srow) * 128 + scol;
    const u16* b0 = w1b + ((long)blockN + cA * 16 + srow) * 128 + scol;
    const u16* b1 = w1b + ((long)blockN + (cA + 1) * 16 + srow) * 128 + scol;
    for (int it = 0; it < 2; ++it) {
        const int k0 = ((it + koff) & 1) << 6;
        #pragma unroll
        for (int p = 0; p < 2; ++p) {
            const int kp = k0 + p * 32;
            __builtin_amdgcn_global_load_lds((const AS1 void*)(a0 + kp), (AS3 void*)&sh.s.As[p][cA * 512],       16, 0, 0);
            __builtin_amdgcn_global_load_lds((const AS1 void*)(a1 + kp), (AS3 void*)&sh.s.As[p][(cA + 1) * 512], 16, 0, 0);
            __builtin_amdgcn_global_load_lds((const AS1 void*)(b0 + kp), (AS3 void*)&sh.s.Bs[p][cA * 512],       16, 0, 0);
            __builtin_amdgcn_global_load_lds((const AS1 void*)(b1 + kp), (AS3 void*)&sh.s.Bs[p][(cA + 1) * 512], 16, 0, 0);
        }
        __syncthreads();
        #pragma unroll
        for (int p = 0; p < 2; ++p) {
            bf16x8 af[4], bfv[4];
            #pragma unroll
            for (int s = 0; s < 4; ++s) {
                af[s]  = *(const bf16x8*)&sh.s.As[p][(wy * 64 + s * 16 + i16) * 32 + q * 8];
                bfv[s] = *(const bf16x8*)&sh.s.Bs[p][(wx * 64 + s * 16 + i16) * 32 + q * 8];
            }
            #pragma unroll
            for (int sm = 0; sm < 4; ++sm)
                #pragma unroll
                for (int sn = 0; sn < 4; ++sn)
                    acc[sm][sn] = __builtin_amdgcn_mfma_f32_16x16x32_bf16(af[sm], bfv[sn], acc[sm][sn], 0, 0, 0);
        }
        __syncthreads();   // also guards obuf overlay of As/Bs
    }

    float bv[4];
    #pragma unroll
    for (int sn = 0; sn < 4; ++sn) bv[sn] = bb[blockN + wx * 64 + sn * 16 + i16];
    #pragma unroll
    for (int sm = 0; sm < 4; ++sm)
        #pragma unroll
        for (int sn = 0; sn < 4; ++sn)
            #pragma unroll
            for (int r = 0; r < 4; ++r)
                sh.obuf[(wy * 64 + sm * 16 + 4 * q + r) * 132 + wx * 64 + sn * 16 + i16] =
                    f2bf(fabsf(acc[sm][sn][r] + bv[sn]));
    __syncthreads();
    const int cg = (tid & 15) * 8;
    #pragma unroll
    for (int it = 0; it < 8; ++it) {
        const int row = it * 16 + (tid >> 4);
        *(u16x8*)&habs[(blockM + row) * 1024 + blockN + cg] =
            *(const u16x8*)&sh.obuf[row * 132 + cg];
    }
}

// ---------------- GEMM2': leaf = habs@Ws^T + xb@Wc^T + cl, fused ragged-max ----------
// (CONTROL: = r13 — BK=64, two linear K segments)
__global__ __launch_bounds__(256) void gemm_leaf(const u16* __restrict__ habs,
        const u16* __restrict__ xb, const u16* __restrict__ wsb,
        const u16* __restrict__ wcb, const float* __restrict__ cl,
        const int* __restrict__ seg, u32* __restrict__ pp) {
    __shared__ u16 As[2][128 * 32];
    __shared__ u16 Bs[2][128 * 32];
    __shared__ u32 pmax[128 * 16];
    const int tid  = threadIdx.x;
    const int lane = tid & 63, wave = tid >> 6;
    const int wy = wave >> 1, wx = wave & 1;
    const int i16 = lane & 15, q = lane >> 4;
    const int xcd = blockIdx.x, y = blockIdx.y;
    const int nTile = y & 7;
    const long blockM = (long)(xcd * 32 + (y >> 3)) * 128;
    const int  blockN = nTile * 128;
    const int  koff = ((y >> 3) * 2) & 15;        // rotation over 16 chunks of K=64

    #pragma unroll
    for (int j = 0; j < 8; ++j) pmax[tid + j * 256] = 0u;   // below all reals

    f32x4 acc[4][4];
    #pragma unroll
    for (int m = 0; m < 4; ++m)
        #pragma unroll
        for (int n = 0; n < 4; ++n) acc[m][n] = f32x4{0.f,0.f,0.f,0.f};

    const int cA = wave * 2, srow = lane >> 2, scol = (lane & 3) * 8;
    // phase 1: habs (stride 1024) x wsb (stride 1024), 16 iters of K=64 (two linear runs)
    {
        const u16* a0 = habs + (blockM + cA * 16 + srow) * 1024 + scol;
        const u16* a1 = habs + (blockM + (cA + 1) * 16 + srow) * 1024 + scol;
        const u16* b0 = wsb + ((long)blockN + cA * 16 + srow) * 1024 + scol;
        const u16* b1 = wsb + ((long)blockN + (cA + 1) * 16 + srow) * 1024 + scol;
        auto kstep = [&](int k0) {
            #pragma unroll
            for (int p = 0; p < 2; ++p) {
                const int kp = k0 + p * 32;
                __builtin_amdgcn_global_load_lds((const AS1 void*)(a0 + kp), (AS3 void*)&As[p][cA * 512],       16, 0, 0);
                __builtin_amdgcn_global_load_lds((const AS1 void*)(a1 + kp), (AS3 void*)&As[p][(cA + 1) * 512], 16, 0, 0);
                __builtin_amdgcn_global_load_lds((const AS1 void*)(b0 + kp), (AS3 void*)&Bs[p][cA * 512],       16, 0, 0);
                __builtin_amdgcn_global_load_lds((const AS1 void*)(b1 + kp), (AS3 void*)&Bs[p][(cA + 1) * 512], 16, 0, 0);
            }
            __syncthreads();
            #pragma unroll
            for (int p = 0; p < 2; ++p) {
                bf16x8 af[4], bfv[4];
                #pragma unroll
                for (int s = 0; s < 4; ++s) {
                    af[s]  = *(const bf16x8*)&As[p][(wy * 64 + s * 16 + i16) * 32 + q * 8];
                    bfv[s] = *(const bf16x8*)&Bs[p][(wx * 64 + s * 16 + i16) * 32 + q * 8];
                }
                #pragma unroll
                for (int sm = 0; sm < 4; ++sm)
                    #pragma unroll
                    for (int sn = 0; sn < 4; ++sn)
                        acc[sm][sn] = __builtin_amdgcn_mfma_f32_16x16x32_bf16(af[sm], bfv[sn], acc[sm][sn], 0, 0, 0);
            }
            __syncthreads();
        };
        for (int it = koff; it < 16; ++it) kstep(it << 6);
        for (int it = 0; it < koff; ++it)  kstep(it << 6);
    }
    // phase 2: xb (stride 128) x wcb (stride 128), 2 iters of K=64
    {
        const u16* a0 = xb + (blockM + cA * 16 + srow) * 128 + scol;
        const u16* a1 = xb + (blockM + (cA + 1) * 16 + srow) * 128 + scol;
        const u16* b0 = wcb + ((long)blockN + cA * 16 + srow) * 128 + scol;
        const u16* b1 = wcb + ((long)blockN + (cA + 1) * 16 + srow) * 128 + scol;
        #pragma unroll
        for (int half = 0; half < 2; ++half) {
            const int k0 = half * 64;
            #pragma unroll
            for (int p = 0; p < 2; ++p) {
                const int kp = k0 + p * 32;
                __builtin_amdgcn_global_load_lds((const AS1 void*)(a0 + kp), (AS3 void*)&As[p][cA * 512],       16, 0, 0);
                __builtin_amdgcn_global_load_lds((const AS1 void*)(a1 + kp), (AS3 void*)&As[p][(cA + 1) * 512], 16, 0, 0);
                __builtin_amdgcn_global_load_lds((const AS1 void*)(b0 + kp), (AS3 void*)&Bs[p][cA * 512],       16, 0, 0);
                __builtin_amdgcn_global_load_lds((const AS1 void*)(b1 + kp), (AS3 void*)&Bs[p][(cA + 1) * 512], 16, 0, 0);
            }
            __syncthreads();
            #pragma unroll
            for (int p = 0; p < 2; ++p) {
                bf16x8 af[4], bfv[4];
                #pragma unroll
                for (int s = 0; s < 4; ++s) {
                    af[s]  = *(const bf16x8*)&As[p][(wy * 64 + s * 16 + i16) * 32 + q * 8];
                    bfv[s] = *(const bf16x8*)&Bs[p][(wx * 64 + s * 16 + i16) * 32 + q * 8];
                }
                #pragma unroll
                for (int sm = 0; sm < 4; ++sm)
                    #pragma unroll
                    for (int sn = 0; sn < 4; ++sn)
                        acc[sm][sn] = __builtin_amdgcn_mfma_f32_16x16x32_bf16(af[sm], bfv[sn], acc[sm][sn], 0, 0, 0);
            }
            __syncthreads();
        }
    }

    // epilogue: D[row = 4q + r][col = i16]; leaf = acc + cl[col]
    int segc[4]; float clv[4];
    #pragma unroll
    for (int sn = 0; sn < 4; ++sn) {
        const int col = blockN + wx * 64 + sn * 16 + i16;
        segc[sn] = seg[col];
        clv[sn]  = cl[col];
    }
    #pragma unroll
    for (int sm = 0; sm < 4; ++sm)
        #pragma unroll
        for (int sn = 0; sn < 4; ++sn)
            #pragma unroll
            for (int r = 0; r < 4; ++r) {
                const int rl = wy * 64 + sm * 16 + 4 * q + r;
                atomicMax(&pmax[rl * 16 + segc[sn]], f2ord(acc[sm][sn][r] + clv[sn]));
            }
    __syncthreads();
    #pragma unroll
    for (int j = 0; j < 8; ++j) {
        int idx = tid + j * 256;                       // 0..2047
        pp[((long)nTile << 19) + ((blockM + (idx >> 4)) << 4) + (idx & 15)] = pmax[idx];
    }
}

// ---------------- finalize: max over 8 partials + softmax ----------------
__global__ __launch_bounds__(256) void finalize(const u32* __restrict__ pp,
                                                float* __restrict__ out) {
    const int tid = threadIdx.x;
    const long row = (long)blockIdx.x * 16 + (tid >> 4);
    const int t = tid & 15;
    u32 m = 0;
    #pragma unroll
    for (int p = 0; p < 8; ++p)
        m = max(m, pp[((long)p << 19) + (row << 4) + t]);
    float logit = ord2f(m);
    float rm = logit;
    #pragma unroll
    for (int d = 8; d >= 1; d >>= 1) rm = fmaxf(rm, __shfl_xor(rm, d, 16));
    float e = __expf(logit - rm);
    float s = e;
    #pragma unroll
    for (int d = 8; d >= 1; d >>= 1) s += __shfl_xor(s, d, 16);
    out[(row << 4) + t] = e / s;
}

// ---------------- launch ----------------
extern "C" void kernel_launch(void* const* d_in, const int* in_sizes, int n_in,
                              void* d_out, int out_size, void* d_ws, size_t ws_size,
                              hipStream_t stream) {
    const float* x  = (const float*)d_in[0];
    const float* Wd = (const float*)d_in[1];
    const float* bd = (const float*)d_in[2];
    const float* Wa = (const float*)d_in[3];
    const float* ba = (const float*)d_in[4];
    const float* Wl = (const float*)d_in[5];
    const int*  seg = (const int*)d_in[6];
    float* out = (float*)d_out;

    char* ws = (char*)d_ws;
    u16*   xb   = (u16*)(ws);                      //   8,388,608 B  x bf16 [32768,128]
    u16*   w1b  = (u16*)(ws + 8388608);            //     262,144 B  W1 bf16 [1024,128]
    float* bb   = (float*)(ws + 8650752);          //       4,096 B  bias [1024]
    u16*   w1t  = (u16*)(ws + 8654848);            //     262,144 B  W1^T bf16 [128,1024]
    u16*   wsb  = (u16*)(ws + 8916992);            //   2,097,152 B  Ws bf16 [1024,1024]
    u16*   dlb  = (u16*)(ws + 11014144);           //   2,097,152 B  Dl bf16 [1024,1024]
    u16*   wcb  = (u16*)(ws + 13111296);           //     262,144 B  Wc bf16 [1024,128]
    float* clp  = (float*)(ws + 13373440);         //       4,096 B  cl fp32 [1024]
    u16*   habs = (u16*)(ws + 13377536);           //  67,108,864 B  |h| bf16 [32768,1024]
    u32*   pp   = (u32*)(ws + 80486400);           //  16,777,216 B  pooledPart u32 [8][32768][16]
    // total ws use: 97,263,616 B (~93 MiB)

    setup_all<<<2624, 256, 0, stream>>>(x, Wd, bd, Wa, ba, Wl,
                                        xb, w1b, bb, w1t, wsb, dlb, clp);
    gemm_hwc <<<dim3(8, 257), 256, 0, stream>>>(xb, w1b, bb, dlb, w1t, habs, wcb);
    gemm_leaf<<<dim3(8, 256), 256, 0, stream>>>(habs, xb, wsb, wcb, clp, seg, pp);
    finalize <<<2048, 256, 0, stream>>>(pp, out);
}